// Round 5
// baseline (289.500 us; speedup 1.0000x reference)
//
#include <hip/hip_runtime.h>

// Problem constants (from reference)
#define VOCAB 50000
#define SEQ   2048
#define BATCH 64
#define DIM   256
#define H1    100
#define H2    150
#define HASH  4096            // per-row hash table (load factor <= 0.5)
#define NCH   8               // chunks per row
#define CHUNK (SEQ / NCH)     // 256
#define NT    1024
#define NWAVE (NT / 64)       // 16

// ---------------------------------------------------------------------------
// ONE kernel, 512 blocks = (row r, chunk c). Each block:
//   - builds the full-row tf hash histogram (redundant x8 per row, ~2us, parallel)
//   - computes tf-idf scores for its 256-token chunk
//   - gathers emb rows for its chunk -> 256-dim partial (float4, coalesced)
//   - writes partial, fences, bumps counters[r]
//   - the 8th arriver of each row reduces 8 partials and runs that row's MLP
// => the 64 MB compulsory emb fetch is spread over all 256 CUs (R4 used 64).
// LDS: 58.4 KB pipeline + 6.5 KB MLP scratch = 64.9 KB -> 2 blocks/CU.
// ---------------------------------------------------------------------------
__global__ __launch_bounds__(1024)
void k_main(const int* __restrict__ x,
            const float* __restrict__ emb,
            const float* __restrict__ idf,
            const float* __restrict__ W1, const float* __restrict__ b1,
            const float* __restrict__ W2, const float* __restrict__ b2,
            const float* __restrict__ W3, const float* __restrict__ b3,
            unsigned* __restrict__ counters,   // [BATCH], zeroed by memset node
            float* __restrict__ partials,      // [BATCH][NCH][DIM]
            float* __restrict__ out) {
    __shared__ int   tok[SEQ];          //  8 KB
    __shared__ int   hkey[HASH];        // 16 KB
    __shared__ int   hcnt[HASH];        // 16 KB
    __shared__ float sc[CHUNK];         //  1 KB
    __shared__ float wacc[NWAVE][DIM];  // 16 KB
    // MLP scratch (only the per-row last block uses these)
    __shared__ float pooled[DIM];       //  1 KB
    __shared__ float hp1[128][4];       //  2 KB
    __shared__ float h1s[112];
    __shared__ float hp2[H2][4];        //  2.4 KB
    __shared__ float h2s[152];
    __shared__ float lg[2];
    __shared__ int   isLast;

    const int bx = blockIdx.x;          // 0..511
    const int r  = bx >> 3;             // batch row
    const int c  = bx & (NCH - 1);      // chunk
    const int t  = threadIdx.x;         // 0..1023
    const int w  = t >> 6, lane = t & 63;
    const int s0 = c * CHUNK;

    // ---- row tokens + hash init ----
    for (int i = t; i < HASH; i += NT) { hkey[i] = -1; hcnt[i] = 0; }
#pragma unroll
    for (int n = 0; n < SEQ / NT; ++n) {
        const int s = n * NT + t;
        tok[s] = x[s * BATCH + r];
    }
    __syncthreads();

    // ---- tf histogram insert (full row; 2 tokens/thread) ----
#pragma unroll
    for (int n = 0; n < SEQ / NT; ++n) {
        const int s = n * NT + t;
        const int mytok = tok[s];
        unsigned h = ((unsigned)mytok * 2654435761u) >> 20;   // top 12 bits
        while (true) {
            int prev = atomicCAS(&hkey[h], -1, mytok);
            if (prev == -1 || prev == mytok) { atomicAdd(&hcnt[h], 1); break; }
            h = (h + 1) & (HASH - 1);
        }
    }
    __syncthreads();

    // ---- scores for this chunk only ----
    if (t < CHUNK) {
        const int s = s0 + t;
        const int mytok = tok[s];
        unsigned h = ((unsigned)mytok * 2654435761u) >> 20;
        while (hkey[h] != mytok) h = (h + 1) & (HASH - 1);
        sc[t] = (mytok == 0) ? 0.0f : (float)hcnt[h] * idf[mytok];
    }
    __syncthreads();

    // ---- gather-pool this chunk: wave w handles 16 s-positions ----
    {
        const float4* embv = (const float4*)emb;   // emb row = 64 float4
        float4 acc = make_float4(0.f, 0.f, 0.f, 0.f);
        const int i0 = w * (CHUNK / NWAVE);
#pragma unroll
        for (int i = 0; i < CHUNK / NWAVE; ++i) {
            const float sv = sc[i0 + i];           // LDS broadcast
            const float4 v = embv[(size_t)tok[s0 + i0 + i] * (DIM / 4) + lane];
            acc.x = fmaf(v.x, sv, acc.x);
            acc.y = fmaf(v.y, sv, acc.y);
            acc.z = fmaf(v.z, sv, acc.z);
            acc.w = fmaf(v.w, sv, acc.w);
        }
        ((float4*)wacc[w])[lane] = acc;
    }
    __syncthreads();

    // ---- reduce waves -> chunk partial; write + release fence ----
    if (t < DIM) {
        float a = 0.0f;
#pragma unroll
        for (int i = 0; i < NWAVE; ++i) a += wacc[i][t];
        partials[(size_t)bx * DIM + t] = a;
        __threadfence();                 // release: partial visible device-wide
    }
    __syncthreads();
    if (t == 0) {
        unsigned prev = atomicAdd(&counters[r], 1u);   // device-scope
        isLast = (prev == NCH - 1);
    }
    __syncthreads();
    if (!isLast) return;

    __threadfence();                     // acquire: see other blocks' partials

    // ---- pooled[d] = sum of this row's 8 chunk partials ----
    if (t < DIM) {
        float a = 0.0f;
#pragma unroll
        for (int cc = 0; cc < NCH; ++cc)
            a += partials[((size_t)r * NCH + cc) * DIM + t];
        pooled[t] = a;
    }
    __syncthreads();

    // ---- stage 1 (100 neurons, k=256): 4 threads/neuron ----
    if (t < 512) {
        const int j = t >> 2;            // 0..127 (j<100 active)
        const int q = t & 3;             // k-quarter
        if (j < H1) {
            const float4* wv = (const float4*)(W1 + j * DIM + q * 64);
            const float4* pv = ((const float4*)pooled) + q * 16;
            float a = 0.0f;
#pragma unroll
            for (int i = 0; i < 16; ++i) {
                const float4 ww = wv[i];
                const float4 pp = pv[i];
                a += ww.x * pp.x + ww.y * pp.y + ww.z * pp.z + ww.w * pp.w;
            }
            hp1[j][q] = a;
        }
    }
    __syncthreads();
    if (t < H1)
        h1s[t] = fmaxf(hp1[t][0] + hp1[t][1] + hp1[t][2] + hp1[t][3] + b1[t], 0.0f);
    __syncthreads();

    // ---- stage 2 (150 neurons, k=100): 4 threads/neuron ----
    if (t < 600) {
        const int j = t >> 2;            // 0..149
        const int q = t & 3;             // k-chunk of 25
        const float* wv = W2 + j * H1 + q * 25;
        float a = 0.0f;
#pragma unroll
        for (int i = 0; i < 25; ++i)
            a = fmaf(wv[i], h1s[q * 25 + i], a);
        hp2[j][q] = a;
    }
    __syncthreads();
    if (t < H2)
        h2s[t] = fmaxf(hp2[t][0] + hp2[t][1] + hp2[t][2] + hp2[t][3] + b2[t], 0.0f);
    __syncthreads();

    // ---- logits + softmax ----
    if (t < 2) {
        const float* wv = W3 + t * H2;
        float a = b3[t];
        for (int k = 0; k < H2; ++k) a = fmaf(wv[k], h2s[k], a);
        lg[t] = a;
    }
    __syncthreads();
    if (t == 0) {
        const float m  = fmaxf(lg[0], lg[1]);
        const float e0 = __expf(lg[0] - m);
        const float e1 = __expf(lg[1] - m);
        const float inv = 1.0f / (e0 + e1);
        out[r * 2 + 0] = e0 * inv;
        out[r * 2 + 1] = e1 * inv;
    }
}

// ---------------------------------------------------------------------------
extern "C" void kernel_launch(void* const* d_in, const int* in_sizes, int n_in,
                              void* d_out, int out_size, void* d_ws, size_t ws_size,
                              hipStream_t stream) {
    const int*   x   = (const int*)  d_in[0];   // [SEQ, BATCH] int32
    const float* emb = (const float*)d_in[1];   // [VOCAB, DIM]
    const float* idf = (const float*)d_in[2];   // [VOCAB]
    const float* W1  = (const float*)d_in[3];   // [H1, DIM]
    const float* b1  = (const float*)d_in[4];   // [H1]
    const float* W2  = (const float*)d_in[5];   // [H2, H1]
    const float* b2  = (const float*)d_in[6];   // [H2]
    const float* W3  = (const float*)d_in[7];   // [2, H2]
    const float* b3  = (const float*)d_in[8];   // [2]
    float* out = (float*)d_out;                 // [BATCH, 2]

    // ws layout: counters[64] (zeroed each call) | partials[512][256]
    unsigned* counters = (unsigned*)d_ws;
    float*    partials = (float*)((char*)d_ws + 1024);

    hipMemsetAsync(counters, 0, BATCH * sizeof(unsigned), stream);
    k_main<<<BATCH * NCH, NT, 0, stream>>>(x, emb, idf, W1, b1, W2, b2, W3, b3,
                                           counters, partials, out);
}

// Round 6
// 127.063 us; speedup vs baseline: 2.2784x; 2.2784x over previous
//
#include <hip/hip_runtime.h>

// Problem constants (from reference)
#define VOCAB 50000
#define SEQ   2048
#define BATCH 64
#define DIM   256
#define H1    100
#define H2    150
#define HASH  4096            // per-row hash table (load factor <= 0.5)
#define NCH   8               // chunks per row
#define CHUNK (SEQ / NCH)     // 256
#define NT    1024
#define NWAVE (NT / 64)       // 16

// ---------------------------------------------------------------------------
// Kernel 1: 512 blocks = (row r, chunk c).  Per block:
//   - full-row tf hash histogram in LDS (redundant x8 per row; parallel, ~4us)
//   - tf-idf scores for its 256-token chunk
//   - emb gather-pool for its chunk -> 256-dim partial (float4, coalesced)
//   - write partial.  NO fences, NO device atomics (R5 post-mortem: agent-scope
//     fences emit L2 writeback/invalidate on CDNA4 -> 4x serialization).
// The kernel boundary provides the device-wide visibility for kernel 2.
// Spreads the compulsory ~64 MB emb fetch over all 256 CUs (R4 used 64:
// per-CU HBM path ~10 B/cy caps 64 CUs at ~1.5 TB/s).
// ---------------------------------------------------------------------------
__global__ __launch_bounds__(1024)
void k_gather(const int* __restrict__ x,
              const float* __restrict__ emb,
              const float* __restrict__ idf,
              float* __restrict__ partials) {    // [BATCH*NCH][DIM]
    __shared__ int   tok[SEQ];          //  8 KB
    __shared__ int   hkey[HASH];        // 16 KB
    __shared__ int   hcnt[HASH];        // 16 KB
    __shared__ float sc[CHUNK];         //  1 KB
    __shared__ float wacc[NWAVE][DIM];  // 16 KB

    const int bx = blockIdx.x;          // 0..511
    const int r  = bx >> 3;             // batch row
    const int c  = bx & (NCH - 1);      // chunk
    const int t  = threadIdx.x;         // 0..1023
    const int w  = t >> 6, lane = t & 63;
    const int s0 = c * CHUNK;

    // ---- row tokens + hash init ----
    for (int i = t; i < HASH; i += NT) { hkey[i] = -1; hcnt[i] = 0; }
#pragma unroll
    for (int n = 0; n < SEQ / NT; ++n) {
        const int s = n * NT + t;
        tok[s] = x[s * BATCH + r];
    }
    __syncthreads();

    // ---- tf histogram insert (full row; 2 tokens/thread) ----
#pragma unroll
    for (int n = 0; n < SEQ / NT; ++n) {
        const int s = n * NT + t;
        const int mytok = tok[s];
        unsigned h = ((unsigned)mytok * 2654435761u) >> 20;   // top 12 bits
        while (true) {
            int prev = atomicCAS(&hkey[h], -1, mytok);        // LDS-local
            if (prev == -1 || prev == mytok) { atomicAdd(&hcnt[h], 1); break; }
            h = (h + 1) & (HASH - 1);
        }
    }
    __syncthreads();

    // ---- scores for this chunk only ----
    if (t < CHUNK) {
        const int s = s0 + t;
        const int mytok = tok[s];
        unsigned h = ((unsigned)mytok * 2654435761u) >> 20;
        while (hkey[h] != mytok) h = (h + 1) & (HASH - 1);
        sc[t] = (mytok == 0) ? 0.0f : (float)hcnt[h] * idf[mytok];
    }
    __syncthreads();

    // ---- gather-pool this chunk: wave w handles 16 s-positions ----
    {
        const float4* embv = (const float4*)emb;   // emb row = 64 float4
        float4 acc = make_float4(0.f, 0.f, 0.f, 0.f);
        const int i0 = w * (CHUNK / NWAVE);
#pragma unroll
        for (int i = 0; i < CHUNK / NWAVE; ++i) {
            const float sv = sc[i0 + i];           // LDS broadcast
            const float4 v = embv[(size_t)tok[s0 + i0 + i] * (DIM / 4) + lane];
            acc.x = fmaf(v.x, sv, acc.x);
            acc.y = fmaf(v.y, sv, acc.y);
            acc.z = fmaf(v.z, sv, acc.z);
            acc.w = fmaf(v.w, sv, acc.w);
        }
        ((float4*)wacc[w])[lane] = acc;
    }
    __syncthreads();

    // ---- reduce waves -> chunk partial (coalesced 1 KB write) ----
    if (t < DIM) {
        float a = 0.0f;
#pragma unroll
        for (int i = 0; i < NWAVE; ++i) a += wacc[i][t];
        partials[(size_t)bx * DIM + t] = a;
    }
}

// ---------------------------------------------------------------------------
// Kernel 2: per-row partial reduce + 3-layer MLP + softmax (R4's proven tail).
// 64 blocks x 1024 threads.
// ---------------------------------------------------------------------------
__global__ __launch_bounds__(1024)
void k_mlp(const float* __restrict__ partials,
           const float* __restrict__ W1, const float* __restrict__ b1,
           const float* __restrict__ W2, const float* __restrict__ b2,
           const float* __restrict__ W3, const float* __restrict__ b3,
           float* __restrict__ out) {
    __shared__ float pooled[DIM];
    __shared__ float hp1[128][4];
    __shared__ float h1s[112];
    __shared__ float hp2[H2][4];
    __shared__ float h2s[152];
    __shared__ float lg[2];
    const int r = blockIdx.x;
    const int t = threadIdx.x;

    if (t < DIM) {
        float a = 0.0f;
#pragma unroll
        for (int cc = 0; cc < NCH; ++cc)
            a += partials[((size_t)r * NCH + cc) * DIM + t];
        pooled[t] = a;
    }
    __syncthreads();

    // stage 1 (100 neurons, k=256): 4 threads/neuron
    if (t < 512) {
        const int j = t >> 2;            // 0..127 (j<100 active)
        const int q = t & 3;             // k-quarter
        if (j < H1) {
            const float4* wv = (const float4*)(W1 + j * DIM + q * 64);
            const float4* pv = ((const float4*)pooled) + q * 16;
            float a = 0.0f;
#pragma unroll
            for (int i = 0; i < 16; ++i) {
                const float4 ww = wv[i];
                const float4 pp = pv[i];
                a += ww.x * pp.x + ww.y * pp.y + ww.z * pp.z + ww.w * pp.w;
            }
            hp1[j][q] = a;
        }
    }
    __syncthreads();
    if (t < H1)
        h1s[t] = fmaxf(hp1[t][0] + hp1[t][1] + hp1[t][2] + hp1[t][3] + b1[t], 0.0f);
    __syncthreads();

    // stage 2 (150 neurons, k=100): 4 threads/neuron
    if (t < 600) {
        const int j = t >> 2;            // 0..149
        const int q = t & 3;             // k-chunk of 25
        const float* wv = W2 + j * H1 + q * 25;
        float a = 0.0f;
#pragma unroll
        for (int i = 0; i < 25; ++i)
            a = fmaf(wv[i], h1s[q * 25 + i], a);
        hp2[j][q] = a;
    }
    __syncthreads();
    if (t < H2)
        h2s[t] = fmaxf(hp2[t][0] + hp2[t][1] + hp2[t][2] + hp2[t][3] + b2[t], 0.0f);
    __syncthreads();

    // logits + softmax
    if (t < 2) {
        const float* wv = W3 + t * H2;
        float a = b3[t];
        for (int k = 0; k < H2; ++k) a = fmaf(wv[k], h2s[k], a);
        lg[t] = a;
    }
    __syncthreads();
    if (t == 0) {
        const float m  = fmaxf(lg[0], lg[1]);
        const float e0 = __expf(lg[0] - m);
        const float e1 = __expf(lg[1] - m);
        const float inv = 1.0f / (e0 + e1);
        out[r * 2 + 0] = e0 * inv;
        out[r * 2 + 1] = e1 * inv;
    }
}

// ---------------------------------------------------------------------------
extern "C" void kernel_launch(void* const* d_in, const int* in_sizes, int n_in,
                              void* d_out, int out_size, void* d_ws, size_t ws_size,
                              hipStream_t stream) {
    const int*   x   = (const int*)  d_in[0];   // [SEQ, BATCH] int32
    const float* emb = (const float*)d_in[1];   // [VOCAB, DIM]
    const float* idf = (const float*)d_in[2];   // [VOCAB]
    const float* W1  = (const float*)d_in[3];   // [H1, DIM]
    const float* b1  = (const float*)d_in[4];   // [H1]
    const float* W2  = (const float*)d_in[5];   // [H2, H1]
    const float* b2  = (const float*)d_in[6];   // [H2]
    const float* W3  = (const float*)d_in[7];   // [2, H2]
    const float* b3  = (const float*)d_in[8];   // [2]
    float* out = (float*)d_out;                 // [BATCH, 2]

    float* partials = (float*)d_ws;             // [512][256] = 512 KB

    k_gather<<<BATCH * NCH, NT, 0, stream>>>(x, emb, idf, partials);
    k_mlp   <<<BATCH, NT, 0, stream>>>(partials, W1, b1, W2, b2, W3, b3, out);
}